// Round 1
// baseline (2164.739 us; speedup 1.0000x reference)
//
#include <hip/hip_runtime.h>
#include <cstdint>

// R5: split the state-independent layer-1 GEMV (cur1 = x@W1^T + b1) out of the
// serial 1-wave/SIMD recurrence into a fully parallel phase-1 kernel (latency
// hidden by occupancy), and make layer 2 a dense register-resident FMA chain
// driven by the wave-uniform ballot mask (bit-exact vs the verified sparse
// ascending-add: fmaf(1,w,c)=fadd_rn(w,c), fmaf(0,w,c)=c exactly).
// Falls back to the previous harness-verified fused kernel if ws too small.

#define TT  512
#define DIN 128
#define HH  64
#define OO  20
#define RPW 32   // rows per wave, phase 1

// ---------------------------------------------------------------------------
// Phase 1: cur1[row][h] = dot(x[row,:], W1[h,:]) + b1[h], bit-identical FMA
// order to the fused kernel (a0..a3 interleave, ((a0+a1)+(a2+a3))+b1).
// ---------------------------------------------------------------------------
__global__ __launch_bounds__(256) void snn_cur1(
    const float* __restrict__ x,      // (nrows, 128)
    const float* __restrict__ W1,     // (64, 128)
    const float* __restrict__ b1,     // (64,)
    float* __restrict__ cur1,         // (nrows, 64)
    int nrows)
{
    const int lane = threadIdx.x & 63;
    const int wid  = threadIdx.x >> 6;
    const int row0 = (blockIdx.x * 4 + wid) * RPW;
    if (row0 >= nrows) return;

    const float* w1p = W1 + lane * DIN;
#define W1LD(i) const float4 w##i = *reinterpret_cast<const float4*>(w1p + 4 * i);
    W1LD(0)  W1LD(1)  W1LD(2)  W1LD(3)  W1LD(4)  W1LD(5)  W1LD(6)  W1LD(7)
    W1LD(8)  W1LD(9)  W1LD(10) W1LD(11) W1LD(12) W1LD(13) W1LD(14) W1LD(15)
    W1LD(16) W1LD(17) W1LD(18) W1LD(19) W1LD(20) W1LD(21) W1LD(22) W1LD(23)
    W1LD(24) W1LD(25) W1LD(26) W1LD(27) W1LD(28) W1LD(29) W1LD(30) W1LD(31)
#undef W1LD
    const float bb1 = b1[lane];

    const float* xr = x    + (size_t)row0 * DIN;   // all lanes same addr: broadcast
    float*       cp = cur1 + (size_t)row0 * HH + lane;
    const int rmax = (row0 + RPW <= nrows) ? RPW : (nrows - row0);

#pragma unroll 2
    for (int r = 0; r < rmax; ++r) {
        float a0 = 0.0f, a1 = 0.0f, a2 = 0.0f, a3 = 0.0f;
#define MAC4(i) { const float4 xk = *reinterpret_cast<const float4*>(xr + 4 * i); \
                  a0 = fmaf(xk.x, w##i.x, a0); a1 = fmaf(xk.y, w##i.y, a1);       \
                  a2 = fmaf(xk.z, w##i.z, a2); a3 = fmaf(xk.w, w##i.w, a3); }
        MAC4(0)  MAC4(1)  MAC4(2)  MAC4(3)  MAC4(4)  MAC4(5)  MAC4(6)  MAC4(7)
        MAC4(8)  MAC4(9)  MAC4(10) MAC4(11) MAC4(12) MAC4(13) MAC4(14) MAC4(15)
        MAC4(16) MAC4(17) MAC4(18) MAC4(19) MAC4(20) MAC4(21) MAC4(22) MAC4(23)
        MAC4(24) MAC4(25) MAC4(26) MAC4(27) MAC4(28) MAC4(29) MAC4(30) MAC4(31)
#undef MAC4
        cp[0] = __fadd_rn(__fadd_rn(__fadd_rn(a0, a1), __fadd_rn(a2, a3)), bb1);
        xr += DIN;
        cp += HH;
    }
}

// ---------------------------------------------------------------------------
// Phase 2: serial recurrence. cur1 prefetched 6 deep in named regs; layer 2 is
// a dense 64-FMA chain from register-held W2 row with wave-uniform 0/1 scalar
// multipliers (bit-exact vs sparse ascending adds); layer 3 stays sparse-LDS
// (s2 almost always 0).
// ---------------------------------------------------------------------------
__global__ __launch_bounds__(64, 1) void snn_recur(
    const float* __restrict__ cur1,   // (B*T, 64)
    const float* __restrict__ beta1,
    const float* __restrict__ W2,     // (64, 64)
    const float* __restrict__ b2,
    const float* __restrict__ beta2,
    const float* __restrict__ W3,     // (20, 64)
    const float* __restrict__ b3,
    const float* __restrict__ beta3,
    float* __restrict__ out)          // (B, T, 20)
{
    __shared__ float sW3T[HH * 21];   // sW3T[j*21+o] = W3[o][j]
    const int lane = threadIdx.x;
    const int b    = blockIdx.x;

    // W2 row `lane` in 16 named float4 registers
    const float* w2p = W2 + lane * HH;
#define W2LD(i) const float4 u##i = *reinterpret_cast<const float4*>(w2p + 4 * i);
    W2LD(0)  W2LD(1)  W2LD(2)  W2LD(3)  W2LD(4)  W2LD(5)  W2LD(6)  W2LD(7)
    W2LD(8)  W2LD(9)  W2LD(10) W2LD(11) W2LD(12) W2LD(13) W2LD(14) W2LD(15)
#undef W2LD

    for (int oo = 0; oo < OO; ++oo) sW3T[lane * 21 + oo] = W3[oo * HH + lane];

    const float bt1 = fminf(fmaxf(beta1[lane], 0.0f), 1.0f);
    const float bb2 = b2[lane];
    const float bt2 = fminf(fmaxf(beta2[lane], 0.0f), 1.0f);
    const int   o   = (lane < OO) ? lane : 0;
    const float bb3 = b3[o];
    const float bt3 = fminf(fmaxf(beta3[o], 0.0f), 1.0f);
    float m1 = 0.0f, m2 = 0.0f, m3 = 0.0f;

    const float* cb   = cur1 + (size_t)b * TT * HH + lane;  // coalesced: 64x4B
    float*       outb = out  + (size_t)b * TT * OO;
    const float* sW3row = sW3T + o;

    // 6-deep prefetch in named registers (1 float/lane/step)
    float p0 = cb[0 * HH], p1 = cb[1 * HH], p2 = cb[2 * HH],
          p3 = cb[3 * HH], p4 = cb[4 * HH], p5 = cb[5 * HH];

#pragma unroll 2
    for (int t = 0; t < TT; ++t) {
        const float cur1v = p0;
        p0 = p1; p1 = p2; p2 = p3; p3 = p4; p4 = p5;
        {
            int tn = t + 6; if (tn >= TT) tn = TT - 1;   // clamp: no OOB on last rows
            p5 = cb[(size_t)tn * HH];
        }

        // layer 1 state update (cur1 precomputed, bit-identical)
        const float r1 = (m1 > 1.0f) ? 1.0f : 0.0f;
        m1 = __fsub_rn(__fadd_rn(__fmul_rn(bt1, m1), cur1v), r1);
        const unsigned long long s1 = __ballot(m1 > 1.0f);

        // layer 2: dense register FMA chain, ascending j, wave-uniform 0/1 mult.
        // fmaf(1,w,c) = fadd_rn(w,c); fmaf(0,w,c) = c exactly -> bit-identical
        // to the verified sparse ascending-add starting from bb2.
        float c2 = bb2;
#define L2J(j, wv) { const float bj = ((s1 >> (j)) & 1ull) ? 1.0f : 0.0f; \
                     c2 = fmaf(bj, (wv), c2); }
#define L2Q(q) L2J(4*(q)+0, u##q.x) L2J(4*(q)+1, u##q.y) \
               L2J(4*(q)+2, u##q.z) L2J(4*(q)+3, u##q.w)
        L2Q(0)  L2Q(1)  L2Q(2)  L2Q(3)  L2Q(4)  L2Q(5)  L2Q(6)  L2Q(7)
        L2Q(8)  L2Q(9)  L2Q(10) L2Q(11) L2Q(12) L2Q(13) L2Q(14) L2Q(15)
#undef L2Q
#undef L2J

        const float r2 = (m2 > 1.0f) ? 1.0f : 0.0f;
        m2 = __fsub_rn(__fadd_rn(__fmul_rn(bt2, m2), c2), r2);
        const unsigned long long s2 = __ballot(m2 > 1.0f);

        // layer 3 (no reset); s2 almost always 0 -> fast scalar skip
        float c3 = bb3;
        if (s2) {
            unsigned long long mm = s2;
            int j = __builtin_ctzll(mm); mm &= (mm - 1);
            float v = sW3row[j * 21];
            while (mm) {
                const int j2 = __builtin_ctzll(mm); mm &= (mm - 1);
                const float v2 = sW3row[j2 * 21];
                c3 = __fadd_rn(c3, v);
                v = v2;
            }
            c3 = __fadd_rn(c3, v);
        }
        m3 = __fadd_rn(__fmul_rn(bt3, m3), c3);
        if (lane < OO) outb[t * OO + lane] = m3;
    }
}

// ---------------------------------------------------------------------------
// Fallback: previous harness-verified fused kernel (unchanged), used if the
// workspace is too small for cur1.
// ---------------------------------------------------------------------------
__global__ __launch_bounds__(64, 1) void snn_fused(
    const float* __restrict__ x,
    const float* __restrict__ W1,
    const float* __restrict__ b1,
    const float* __restrict__ beta1,
    const float* __restrict__ W2,
    const float* __restrict__ b2,
    const float* __restrict__ beta2,
    const float* __restrict__ W3,
    const float* __restrict__ b3,
    const float* __restrict__ beta3,
    float* __restrict__ out)
{
    __shared__ float sW2T[HH * 65];
    __shared__ float sW3T[HH * 21];
    __shared__ float sx[8 * DIN];

    const int lane = threadIdx.x;
    const int b    = blockIdx.x;

    const float* w1p = W1 + lane * DIN;
#define W1LD(i) const float4 w##i = *reinterpret_cast<const float4*>(w1p + 4 * i);
    W1LD(0)  W1LD(1)  W1LD(2)  W1LD(3)  W1LD(4)  W1LD(5)  W1LD(6)  W1LD(7)
    W1LD(8)  W1LD(9)  W1LD(10) W1LD(11) W1LD(12) W1LD(13) W1LD(14) W1LD(15)
    W1LD(16) W1LD(17) W1LD(18) W1LD(19) W1LD(20) W1LD(21) W1LD(22) W1LD(23)
    W1LD(24) W1LD(25) W1LD(26) W1LD(27) W1LD(28) W1LD(29) W1LD(30) W1LD(31)
#undef W1LD

    for (int h = 0; h < HH; ++h)  sW2T[lane * 65 + h]  = W2[h * HH + lane];
    for (int oo = 0; oo < OO; ++oo) sW3T[lane * 21 + oo] = W3[oo * HH + lane];

    const float bb1 = b1[lane];
    const float bt1 = fminf(fmaxf(beta1[lane], 0.0f), 1.0f);
    const float bb2 = b2[lane];
    const float bt2 = fminf(fmaxf(beta2[lane], 0.0f), 1.0f);
    const int   o   = (lane < OO) ? lane : 0;
    const float bb3 = b3[o];
    const float bt3 = fminf(fmaxf(beta3[o], 0.0f), 1.0f);
    float m1 = 0.0f, m2 = 0.0f, m3 = 0.0f;

    const float* xb   = x   + (size_t)b * TT * DIN;
    float*       outb = out + (size_t)b * TT * OO;
    const float* sW2row = sW2T + lane;
    const float* sW3row = sW3T + o;

    const float4 v0 = *reinterpret_cast<const float4*>(xb + 0 * DIN + 4 * lane);
    const float4 v1 = *reinterpret_cast<const float4*>(xb + 2 * DIN + 4 * lane);
    float4 pr = *reinterpret_cast<const float4*>(xb + 4 * DIN + 4 * lane);
    float4 pf = *reinterpret_cast<const float4*>(xb + 6 * DIN + 4 * lane);
    *reinterpret_cast<float4*>(sx + 0 * DIN + 4 * lane) = v0;
    *reinterpret_cast<float4*>(sx + 2 * DIN + 4 * lane) = v1;

    for (int t = 0; t < TT; ++t) {
        const float* xr = sx + (t & 7) * DIN;
        float a0 = 0.0f, a1 = 0.0f, a2 = 0.0f, a3 = 0.0f;
#define MAC4(i) { const float4 xk = *reinterpret_cast<const float4*>(xr + 4 * i); \
                  a0 = fmaf(xk.x, w##i.x, a0); a1 = fmaf(xk.y, w##i.y, a1);       \
                  a2 = fmaf(xk.z, w##i.z, a2); a3 = fmaf(xk.w, w##i.w, a3); }
        MAC4(0)  MAC4(1)  MAC4(2)  MAC4(3)  MAC4(4)  MAC4(5)  MAC4(6)  MAC4(7)
        MAC4(8)  MAC4(9)  MAC4(10) MAC4(11) MAC4(12) MAC4(13) MAC4(14) MAC4(15)
        MAC4(16) MAC4(17) MAC4(18) MAC4(19) MAC4(20) MAC4(21) MAC4(22) MAC4(23)
        MAC4(24) MAC4(25) MAC4(26) MAC4(27) MAC4(28) MAC4(29) MAC4(30) MAC4(31)
#undef MAC4
        const float cur1 = __fadd_rn(__fadd_rn(__fadd_rn(a0, a1), __fadd_rn(a2, a3)), bb1);

        const float r1 = (m1 > 1.0f) ? 1.0f : 0.0f;
        m1 = __fsub_rn(__fadd_rn(__fmul_rn(bt1, m1), cur1), r1);
        const unsigned long long s1 = __ballot(m1 > 1.0f);

        float c2 = bb2;
        {
            unsigned long long mm = s1;
            if (mm) {
                int j = __builtin_ctzll(mm); mm &= (mm - 1);
                float v = sW2row[j * 65];
                while (mm) {
                    const int j2 = __builtin_ctzll(mm); mm &= (mm - 1);
                    const float v2 = sW2row[j2 * 65];
                    c2 = __fadd_rn(c2, v);
                    v = v2;
                }
                c2 = __fadd_rn(c2, v);
            }
        }
        const float r2 = (m2 > 1.0f) ? 1.0f : 0.0f;
        m2 = __fsub_rn(__fadd_rn(__fmul_rn(bt2, m2), c2), r2);
        const unsigned long long s2 = __ballot(m2 > 1.0f);

        float c3 = bb3;
        if (s2) {
            unsigned long long mm = s2;
            int j = __builtin_ctzll(mm); mm &= (mm - 1);
            float v = sW3row[j * 21];
            while (mm) {
                const int j2 = __builtin_ctzll(mm); mm &= (mm - 1);
                const float v2 = sW3row[j2 * 21];
                c3 = __fadd_rn(c3, v);
                v = v2;
            }
            c3 = __fadd_rn(c3, v);
        }
        m3 = __fadd_rn(__fmul_rn(bt3, m3), c3);
        if (lane < OO) outb[t * OO + lane] = m3;

        if (((t & 1) == 0) && (t + 4 < TT)) {
            *reinterpret_cast<float4*>(sx + ((t + 4) & 7) * DIN + 4 * lane) = pr;
            pr = pf;
            if (t + 8 < TT) {
                pf = *reinterpret_cast<const float4*>(xb + (t + 8) * DIN + 4 * lane);
            }
        }
    }
}

extern "C" void kernel_launch(void* const* d_in, const int* in_sizes, int n_in,
                              void* d_out, int out_size, void* d_ws, size_t ws_size,
                              hipStream_t stream) {
    const float* x     = (const float*)d_in[0];
    const float* W1    = (const float*)d_in[1];
    const float* b1    = (const float*)d_in[2];
    const float* beta1 = (const float*)d_in[3];
    const float* W2    = (const float*)d_in[4];
    const float* b2    = (const float*)d_in[5];
    const float* beta2 = (const float*)d_in[6];
    const float* W3    = (const float*)d_in[7];
    const float* b3    = (const float*)d_in[8];
    const float* beta3 = (const float*)d_in[9];

    const int B = in_sizes[0] / (TT * DIN);   // 1024
    const int nrows = B * TT;
    const size_t need = (size_t)nrows * HH * sizeof(float);  // 128 MiB at B=1024

    if (d_ws != nullptr && ws_size >= need) {
        const int blocks1 = (nrows + 4 * RPW - 1) / (4 * RPW);
        snn_cur1<<<dim3(blocks1), dim3(256), 0, stream>>>(
            x, W1, b1, (float*)d_ws, nrows);
        snn_recur<<<dim3(B), dim3(64), 0, stream>>>(
            (const float*)d_ws, beta1, W2, b2, beta2, W3, b3, beta3,
            (float*)d_out);
    } else {
        snn_fused<<<dim3(B), dim3(64), 0, stream>>>(
            x, W1, b1, beta1, W2, b2, beta2, W3, b3, beta3, (float*)d_out);
    }
}

// Round 3
// 880.988 us; speedup vs baseline: 2.4572x; 2.4572x over previous
//
#include <hip/hip_runtime.h>
#include <cstdint>

// R7: R6 post-mortem — absmax 129.77 exceeds the structural bound (|m3|<=16.4
// even with garbage cur1), so the failure had to be non-m3 BYTES in out. The
// only candidate: R6's sOut flush wrote LDS as scalar float but read it as
// float4 (mixed-type LDS access -> TBAA may license reordering the read above
// the writes -> uninitialized-LDS garbage). Fix: stage the 16 per-step outputs
// in NAMED REGISTERS and flush with lane-guarded scalar stores (the verified
// R4 store pattern, batched). Phase-1 keeps the R6 tiled-GEMV structure
// (audited clean; float4 both ways) with 256 threads for 2 waves/SIMD.
// All arithmetic orders operand-identical to the verified R4/R5 kernels.

#define TT  512
#define DIN 128
#define HH  64
#define OO  20
#define S1P 132   // LDS row stride (floats): sW rows land on distinct banks

// ---------------------------------------------------------------------------
// Phase 1: cur1[row][h] = dot(x[row,:], W1[h,:]) + b1[h]
// 64 rows x 64 h per block, 256 threads: 4 rows x 4 h each.
// Bit-exact per (row,h): comp .x takes k=0,4,8,... ascending, etc.;
// combine ((ax+ay)+(az+aw)) + b1.
// ---------------------------------------------------------------------------
__global__ __launch_bounds__(256, 1) void snn_cur1(
    const float* __restrict__ x,      // (nrows, 128)
    const float* __restrict__ W1,     // (64, 128)
    const float* __restrict__ b1,     // (64,)
    float* __restrict__ cur1,         // (nrows, 64)
    int nrows)
{
    __shared__ float sX[64 * S1P];
    __shared__ float sW[64 * S1P];
    const int tid  = threadIdx.x;
    const int row0 = blockIdx.x * 64;

    // stage x tile (64 rows) and W1 (64 rows): 2048 float4 each, 8 per thread
    const float* xb = x + (size_t)row0 * DIN;
#pragma unroll
    for (int p = 0; p < 8; ++p) {
        const int idx = tid + p * 256;        // 0..2047
        const int r   = idx >> 5;             // 0..63
        const int kq  = (idx & 31) << 2;      // 0..124
        *reinterpret_cast<float4*>(sX + r * S1P + kq) =
            *reinterpret_cast<const float4*>(xb + r * DIN + kq);
        *reinterpret_cast<float4*>(sW + r * S1P + kq) =
            *reinterpret_cast<const float4*>(W1 + r * DIN + kq);
    }
    __syncthreads();

    const int hq = tid & 15;                  // h = hq + 16*i, i=0..3
    const int rq = tid >> 4;                  // rows rq*4 .. rq*4+3
    const float* xrow = sX + rq * 4 * S1P;
    const float* wrow = sW + hq * S1P;

#define DECLA(i) float4 A##i##0 = {0.f,0.f,0.f,0.f}, A##i##1 = {0.f,0.f,0.f,0.f}, \
                        A##i##2 = {0.f,0.f,0.f,0.f}, A##i##3 = {0.f,0.f,0.f,0.f};
    DECLA(0) DECLA(1) DECLA(2) DECLA(3)
#undef DECLA

#define PH1FMA(i, r) \
    A##i##r.x = fmaf(xv##r.x, wv##i.x, A##i##r.x); \
    A##i##r.y = fmaf(xv##r.y, wv##i.y, A##i##r.y); \
    A##i##r.z = fmaf(xv##r.z, wv##i.z, A##i##r.z); \
    A##i##r.w = fmaf(xv##r.w, wv##i.w, A##i##r.w);

#pragma unroll 4
    for (int c = 0; c < 32; ++c) {
        const int k0 = c << 2;
        const float4 xv0 = *reinterpret_cast<const float4*>(xrow + 0 * S1P + k0);
        const float4 xv1 = *reinterpret_cast<const float4*>(xrow + 1 * S1P + k0);
        const float4 xv2 = *reinterpret_cast<const float4*>(xrow + 2 * S1P + k0);
        const float4 xv3 = *reinterpret_cast<const float4*>(xrow + 3 * S1P + k0);
        const float4 wv0 = *reinterpret_cast<const float4*>(wrow + 0 * 16 * S1P + k0);
        const float4 wv1 = *reinterpret_cast<const float4*>(wrow + 1 * 16 * S1P + k0);
        const float4 wv2 = *reinterpret_cast<const float4*>(wrow + 2 * 16 * S1P + k0);
        const float4 wv3 = *reinterpret_cast<const float4*>(wrow + 3 * 16 * S1P + k0);
        PH1FMA(0,0) PH1FMA(0,1) PH1FMA(0,2) PH1FMA(0,3)
        PH1FMA(1,0) PH1FMA(1,1) PH1FMA(1,2) PH1FMA(1,3)
        PH1FMA(2,0) PH1FMA(2,1) PH1FMA(2,2) PH1FMA(2,3)
        PH1FMA(3,0) PH1FMA(3,1) PH1FMA(3,2) PH1FMA(3,3)
    }
#undef PH1FMA

    const float bh0 = b1[hq];
    const float bh1 = b1[hq + 16];
    const float bh2 = b1[hq + 32];
    const float bh3 = b1[hq + 48];

#define PH1OUT(i, r, BB) \
    cur1[(size_t)(row0 + rq * 4 + r) * HH + hq + 16 * i] = \
        __fadd_rn(__fadd_rn(__fadd_rn(A##i##r.x, A##i##r.y), \
                            __fadd_rn(A##i##r.z, A##i##r.w)), BB);
    PH1OUT(0,0,bh0) PH1OUT(0,1,bh0) PH1OUT(0,2,bh0) PH1OUT(0,3,bh0)
    PH1OUT(1,0,bh1) PH1OUT(1,1,bh1) PH1OUT(1,2,bh1) PH1OUT(1,3,bh1)
    PH1OUT(2,0,bh2) PH1OUT(2,1,bh2) PH1OUT(2,2,bh2) PH1OUT(2,3,bh2)
    PH1OUT(3,0,bh3) PH1OUT(3,1,bh3) PH1OUT(3,2,bh3) PH1OUT(3,3,bh3)
#undef PH1OUT
}

// ---------------------------------------------------------------------------
// Phase 2: serial recurrence, 16-step blocks. Loads batched at block start;
// per-step m3 staged in NAMED REGISTERS, flushed with lane-guarded scalar
// stores at block end (verified R4 store pattern, batched). No out-LDS.
// ---------------------------------------------------------------------------
__global__ __launch_bounds__(64, 1) void snn_recur(
    const float* __restrict__ cur1,   // (B*T, 64)
    const float* __restrict__ beta1,
    const float* __restrict__ W2,     // (64, 64)
    const float* __restrict__ b2,
    const float* __restrict__ beta2,
    const float* __restrict__ W3,     // (20, 64)
    const float* __restrict__ b3,
    const float* __restrict__ beta3,
    float* __restrict__ out)          // (B, T, 20)
{
    __shared__ float sW3T[HH * 21];   // sW3T[j*21+o] = W3[o][j] (float both ways)
    const int lane = threadIdx.x;
    const int b    = blockIdx.x;

    // W2 row `lane` in 16 named float4 registers
    const float* w2p = W2 + lane * HH;
#define W2LD(i) const float4 u##i = *reinterpret_cast<const float4*>(w2p + 4 * i);
    W2LD(0)  W2LD(1)  W2LD(2)  W2LD(3)  W2LD(4)  W2LD(5)  W2LD(6)  W2LD(7)
    W2LD(8)  W2LD(9)  W2LD(10) W2LD(11) W2LD(12) W2LD(13) W2LD(14) W2LD(15)
#undef W2LD

    for (int oo = 0; oo < OO; ++oo) sW3T[lane * 21 + oo] = W3[oo * HH + lane];

    const float bt1 = fminf(fmaxf(beta1[lane], 0.0f), 1.0f);
    const float bb2 = b2[lane];
    const float bt2 = fminf(fmaxf(beta2[lane], 0.0f), 1.0f);
    const int   o   = (lane < OO) ? lane : 0;
    const float bb3 = b3[o];
    const float bt3 = fminf(fmaxf(beta3[o], 0.0f), 1.0f);
    float m1 = 0.0f, m2 = 0.0f, m3 = 0.0f;

    const float* cb   = cur1 + (size_t)b * TT * HH + lane;  // coalesced 256B/step
    float*       outb = out  + (size_t)b * TT * OO;
    const float* sW3row = sW3T + o;

    // layer-2 dense chain: ascending j, wave-uniform 0/1 multipliers.
    // fmaf(1,w,c)=fadd_rn(w,c), fmaf(0,w,c)=c exactly -> bit-identical to the
    // verified sparse ascending-add starting from bb2.
#define L2J(j, wv) { const float bj = ((s1m >> (j)) & 1ull) ? 1.0f : 0.0f; \
                     c2 = fmaf(bj, (wv), c2); }
#define L2Q(q) L2J(4*(q)+0, u##q.x) L2J(4*(q)+1, u##q.y) \
               L2J(4*(q)+2, u##q.z) L2J(4*(q)+3, u##q.w)

#define STEP(CURV, GVAR) { \
    const float r1v = (m1 > 1.0f) ? 1.0f : 0.0f; \
    m1 = __fsub_rn(__fadd_rn(__fmul_rn(bt1, m1), (CURV)), r1v); \
    const unsigned long long s1m = __ballot(m1 > 1.0f); \
    float c2 = bb2; \
    L2Q(0)  L2Q(1)  L2Q(2)  L2Q(3)  L2Q(4)  L2Q(5)  L2Q(6)  L2Q(7) \
    L2Q(8)  L2Q(9)  L2Q(10) L2Q(11) L2Q(12) L2Q(13) L2Q(14) L2Q(15) \
    const float r2v = (m2 > 1.0f) ? 1.0f : 0.0f; \
    m2 = __fsub_rn(__fadd_rn(__fmul_rn(bt2, m2), c2), r2v); \
    const unsigned long long s2m = __ballot(m2 > 1.0f); \
    float c3 = bb3; \
    if (s2m) { \
        unsigned long long mm = s2m; \
        int jj = __builtin_ctzll(mm); mm &= (mm - 1); \
        float vv = sW3row[jj * 21]; \
        while (mm) { \
            const int j2 = __builtin_ctzll(mm); mm &= (mm - 1); \
            const float v2 = sW3row[j2 * 21]; \
            c3 = __fadd_rn(c3, vv); \
            vv = v2; \
        } \
        c3 = __fadd_rn(c3, vv); \
    } \
    m3 = __fadd_rn(__fmul_rn(bt3, m3), c3); \
    GVAR = m3; \
}

    // prologue: steps 0..15 in flight
    float q0  = cb[0*HH],  q1  = cb[1*HH],  q2  = cb[2*HH],  q3  = cb[3*HH];
    float q4  = cb[4*HH],  q5  = cb[5*HH],  q6  = cb[6*HH],  q7  = cb[7*HH];
    float q8  = cb[8*HH],  q9  = cb[9*HH],  q10 = cb[10*HH], q11 = cb[11*HH];
    float q12 = cb[12*HH], q13 = cb[13*HH], q14 = cb[14*HH], q15 = cb[15*HH];

#pragma unroll 1
    for (int tb = 0; tb < TT; tb += 16) {
        // batch-issue next block's loads (oldest vmem ops of this iteration)
        float n0 = 0.f, n1 = 0.f, n2 = 0.f, n3 = 0.f, n4 = 0.f, n5 = 0.f,
              n6 = 0.f, n7 = 0.f, n8 = 0.f, n9 = 0.f, n10 = 0.f, n11 = 0.f,
              n12 = 0.f, n13 = 0.f, n14 = 0.f, n15 = 0.f;
        if (tb + 16 < TT) {
            const float* cn = cb + (size_t)(tb + 16) * HH;
            n0  = cn[0*HH];  n1  = cn[1*HH];  n2  = cn[2*HH];  n3  = cn[3*HH];
            n4  = cn[4*HH];  n5  = cn[5*HH];  n6  = cn[6*HH];  n7  = cn[7*HH];
            n8  = cn[8*HH];  n9  = cn[9*HH];  n10 = cn[10*HH]; n11 = cn[11*HH];
            n12 = cn[12*HH]; n13 = cn[13*HH]; n14 = cn[14*HH]; n15 = cn[15*HH];
        }

        float g0, g1, g2, g3, g4, g5, g6, g7,
              g8, g9, g10, g11, g12, g13, g14, g15;
        STEP(q0, g0)   STEP(q1, g1)   STEP(q2, g2)   STEP(q3, g3)
        STEP(q4, g4)   STEP(q5, g5)   STEP(q6, g6)   STEP(q7, g7)
        STEP(q8, g8)   STEP(q9, g9)   STEP(q10, g10) STEP(q11, g11)
        STEP(q12, g12) STEP(q13, g13) STEP(q14, g14) STEP(q15, g15)

        // flush: 16 lane-guarded scalar stores (identical addressing to R4)
        if (lane < OO) {
            float* op = outb + (size_t)tb * OO + lane;
            op[0*OO]  = g0;  op[1*OO]  = g1;  op[2*OO]  = g2;  op[3*OO]  = g3;
            op[4*OO]  = g4;  op[5*OO]  = g5;  op[6*OO]  = g6;  op[7*OO]  = g7;
            op[8*OO]  = g8;  op[9*OO]  = g9;  op[10*OO] = g10; op[11*OO] = g11;
            op[12*OO] = g12; op[13*OO] = g13; op[14*OO] = g14; op[15*OO] = g15;
        }

        q0 = n0;  q1 = n1;  q2 = n2;  q3 = n3;  q4 = n4;  q5 = n5;
        q6 = n6;  q7 = n7;  q8 = n8;  q9 = n9;  q10 = n10; q11 = n11;
        q12 = n12; q13 = n13; q14 = n14; q15 = n15;
    }
#undef STEP
#undef L2Q
#undef L2J
}

// ---------------------------------------------------------------------------
// Fallback: harness-verified fused kernel (unchanged), used if ws too small.
// ---------------------------------------------------------------------------
__global__ __launch_bounds__(64, 1) void snn_fused(
    const float* __restrict__ x,
    const float* __restrict__ W1,
    const float* __restrict__ b1,
    const float* __restrict__ beta1,
    const float* __restrict__ W2,
    const float* __restrict__ b2,
    const float* __restrict__ beta2,
    const float* __restrict__ W3,
    const float* __restrict__ b3,
    const float* __restrict__ beta3,
    float* __restrict__ out)
{
    __shared__ float sW2T[HH * 65];
    __shared__ float sW3T[HH * 21];
    __shared__ float sx[8 * DIN];

    const int lane = threadIdx.x;
    const int b    = blockIdx.x;

    const float* w1p = W1 + lane * DIN;
#define W1LD(i) const float4 w##i = *reinterpret_cast<const float4*>(w1p + 4 * i);
    W1LD(0)  W1LD(1)  W1LD(2)  W1LD(3)  W1LD(4)  W1LD(5)  W1LD(6)  W1LD(7)
    W1LD(8)  W1LD(9)  W1LD(10) W1LD(11) W1LD(12) W1LD(13) W1LD(14) W1LD(15)
    W1LD(16) W1LD(17) W1LD(18) W1LD(19) W1LD(20) W1LD(21) W1LD(22) W1LD(23)
    W1LD(24) W1LD(25) W1LD(26) W1LD(27) W1LD(28) W1LD(29) W1LD(30) W1LD(31)
#undef W1LD

    for (int h = 0; h < HH; ++h)  sW2T[lane * 65 + h]  = W2[h * HH + lane];
    for (int oo = 0; oo < OO; ++oo) sW3T[lane * 21 + oo] = W3[oo * HH + lane];

    const float bb1 = b1[lane];
    const float bt1 = fminf(fmaxf(beta1[lane], 0.0f), 1.0f);
    const float bb2 = b2[lane];
    const float bt2 = fminf(fmaxf(beta2[lane], 0.0f), 1.0f);
    const int   o   = (lane < OO) ? lane : 0;
    const float bb3 = b3[o];
    const float bt3 = fminf(fmaxf(beta3[o], 0.0f), 1.0f);
    float m1 = 0.0f, m2 = 0.0f, m3 = 0.0f;

    const float* xb   = x   + (size_t)b * TT * DIN;
    float*       outb = out + (size_t)b * TT * OO;
    const float* sW2row = sW2T + lane;
    const float* sW3row = sW3T + o;

    const float4 v0 = *reinterpret_cast<const float4*>(xb + 0 * DIN + 4 * lane);
    const float4 v1 = *reinterpret_cast<const float4*>(xb + 2 * DIN + 4 * lane);
    float4 pr = *reinterpret_cast<const float4*>(xb + 4 * DIN + 4 * lane);
    float4 pf = *reinterpret_cast<const float4*>(xb + 6 * DIN + 4 * lane);
    *reinterpret_cast<float4*>(sx + 0 * DIN + 4 * lane) = v0;
    *reinterpret_cast<float4*>(sx + 2 * DIN + 4 * lane) = v1;

    for (int t = 0; t < TT; ++t) {
        const float* xr = sx + (t & 7) * DIN;
        float a0 = 0.0f, a1 = 0.0f, a2 = 0.0f, a3 = 0.0f;
#define MAC4(i) { const float4 xk = *reinterpret_cast<const float4*>(xr + 4 * i); \
                  a0 = fmaf(xk.x, w##i.x, a0); a1 = fmaf(xk.y, w##i.y, a1);       \
                  a2 = fmaf(xk.z, w##i.z, a2); a3 = fmaf(xk.w, w##i.w, a3); }
        MAC4(0)  MAC4(1)  MAC4(2)  MAC4(3)  MAC4(4)  MAC4(5)  MAC4(6)  MAC4(7)
        MAC4(8)  MAC4(9)  MAC4(10) MAC4(11) MAC4(12) MAC4(13) MAC4(14) MAC4(15)
        MAC4(16) MAC4(17) MAC4(18) MAC4(19) MAC4(20) MAC4(21) MAC4(22) MAC4(23)
        MAC4(24) MAC4(25) MAC4(26) MAC4(27) MAC4(28) MAC4(29) MAC4(30) MAC4(31)
#undef MAC4
        const float cur1 = __fadd_rn(__fadd_rn(__fadd_rn(a0, a1), __fadd_rn(a2, a3)), bb1);

        const float r1 = (m1 > 1.0f) ? 1.0f : 0.0f;
        m1 = __fsub_rn(__fadd_rn(__fmul_rn(bt1, m1), cur1), r1);
        const unsigned long long s1 = __ballot(m1 > 1.0f);

        float c2 = bb2;
        {
            unsigned long long mm = s1;
            if (mm) {
                int j = __builtin_ctzll(mm); mm &= (mm - 1);
                float v = sW2row[j * 65];
                while (mm) {
                    const int j2 = __builtin_ctzll(mm); mm &= (mm - 1);
                    const float v2 = sW2row[j2 * 65];
                    c2 = __fadd_rn(c2, v);
                    v = v2;
                }
                c2 = __fadd_rn(c2, v);
            }
        }
        const float r2 = (m2 > 1.0f) ? 1.0f : 0.0f;
        m2 = __fsub_rn(__fadd_rn(__fmul_rn(bt2, m2), c2), r2);
        const unsigned long long s2 = __ballot(m2 > 1.0f);

        float c3 = bb3;
        if (s2) {
            unsigned long long mm = s2;
            int j = __builtin_ctzll(mm); mm &= (mm - 1);
            float v = sW3row[j * 21];
            while (mm) {
                const int j2 = __builtin_ctzll(mm); mm &= (mm - 1);
                const float v2 = sW3row[j2 * 21];
                c3 = __fadd_rn(c3, v);
                v = v2;
            }
            c3 = __fadd_rn(c3, v);
        }
        m3 = __fadd_rn(__fmul_rn(bt3, m3), c3);
        if (lane < OO) outb[t * OO + lane] = m3;

        if (((t & 1) == 0) && (t + 4 < TT)) {
            *reinterpret_cast<float4*>(sx + ((t + 4) & 7) * DIN + 4 * lane) = pr;
            pr = pf;
            if (t + 8 < TT) {
                pf = *reinterpret_cast<const float4*>(xb + (t + 8) * DIN + 4 * lane);
            }
        }
    }
}

extern "C" void kernel_launch(void* const* d_in, const int* in_sizes, int n_in,
                              void* d_out, int out_size, void* d_ws, size_t ws_size,
                              hipStream_t stream) {
    const float* x     = (const float*)d_in[0];
    const float* W1    = (const float*)d_in[1];
    const float* b1    = (const float*)d_in[2];
    const float* beta1 = (const float*)d_in[3];
    const float* W2    = (const float*)d_in[4];
    const float* b2    = (const float*)d_in[5];
    const float* beta2 = (const float*)d_in[6];
    const float* W3    = (const float*)d_in[7];
    const float* b3    = (const float*)d_in[8];
    const float* beta3 = (const float*)d_in[9];

    const int B = in_sizes[0] / (TT * DIN);   // 1024
    const int nrows = B * TT;                 // divisible by 64 (TT=512)
    const size_t need = (size_t)nrows * HH * sizeof(float);  // 128 MiB at B=1024

    if (d_ws != nullptr && ws_size >= need) {
        snn_cur1<<<dim3(nrows / 64), dim3(256), 0, stream>>>(
            x, W1, b1, (float*)d_ws, nrows);
        snn_recur<<<dim3(B), dim3(64), 0, stream>>>(
            (const float*)d_ws, beta1, W2, b2, beta2, W3, b3, beta3,
            (float*)d_out);
    } else {
        snn_fused<<<dim3(B), dim3(64), 0, stream>>>(
            x, W1, b1, beta1, W2, b2, beta2, W3, b3, beta3, (float*)d_out);
    }
}